// Round 6
// baseline (272.835 us; speedup 1.0000x reference)
//
#include <hip/hip_runtime.h>

#define BATCH 16
#define CH    64
#define LEN   4096
#define NCODE 1024
#define NPTS  (BATCH * LEN)   // 65536
#define NSLICE 4              // K-slices per block (one wave each)
#define KB     8              // codes per k-block (x-reuse factor)

typedef float float4v __attribute__((ext_vector_type(4)));

// ---------------------------------------------------------------------------
// Kernel 0: transpose x (B,C,L) -> xt (B*L, C) so each point's channels are
// contiguous (argmin reloads x per k-block as dwordx4 with imm offsets).
// ---------------------------------------------------------------------------
__global__ __launch_bounds__(256) void vq_transpose(const float* __restrict__ x,
                                                    float* __restrict__ xt) {
    __shared__ float tile[64][65];
    const int b  = blockIdx.x >> 6;    // 16 batches x 64 l-chunks
    const int l0 = (blockIdx.x & 63) * 64;
    const int t  = threadIdx.x;
#pragma unroll
    for (int r = 0; r < 16; ++r) {
        int c = r * 4 + (t >> 6);
        int l = t & 63;
        tile[c][l] = x[((size_t)b * CH + c) * LEN + l0 + l];
    }
    __syncthreads();
#pragma unroll
    for (int r = 0; r < 16; ++r) {
        int l = r * 4 + (t >> 6);
        int c = t & 63;
        xt[((size_t)b * LEN + l0 + l) * CH + c] = tile[c][l];
    }
}

// ---------------------------------------------------------------------------
// Kernel 1: w2[k] = sum_c codebook[k,c]^2
// ---------------------------------------------------------------------------
__global__ __launch_bounds__(256) void vq_w2(const float* __restrict__ cb,
                                             float* __restrict__ w2) {
    int k = blockIdx.x * 256 + threadIdx.x;
    if (k < NCODE) {
        const float* w = cb + (size_t)k * CH;
        float s = 0.f;
#pragma unroll
        for (int c = 0; c < CH; ++c) s = fmaf(w[c], w[c], s);
        w2[k] = s;
    }
}

// ---------------------------------------------------------------------------
// Kernel 2: per-point argmin. 256 thr = 64 points x 4 K-slices (256 codes ea).
// K-blocked: per 8 codes, reload 32 channels of x (float4s) and reuse each
// value 8x. Live set ~50 VGPRs -> fits the RA's 64-VGPR/8-wave budget, so
// nothing spills and remat-from-memory is unprofitable (rounds 2-5: per-code
// x re-reads = 4.3 GB L1 traffic = the 55-78% stall). The asm on xp blocks
// LICM from re-hoisting the loads across k-blocks.
// ---------------------------------------------------------------------------
__global__ __launch_bounds__(256) void vq_argmin(const float*  __restrict__ xt,
                                                 const float*  __restrict__ cbk,
                                                 const float*  __restrict__ w2,
                                                 float*        __restrict__ idx_out,
                                                 double*       __restrict__ partial) {
    const int t     = threadIdx.x;
    const int pt    = t & 63;                                  // point within block
    const int slice = __builtin_amdgcn_readfirstlane(t >> 6);  // 0..3, scalar
    const int p     = blockIdx.x * 64 + pt;                    // global point id

    const float* xp = xt + (size_t)p * CH;

    // |x|^2 once (also warms L1 with this wave's 16KB x-block).
    float x2 = 0.f;
#pragma unroll
    for (int q = 0; q < 16; ++q) {
        float4v v = *(const float4v*)(xp + 4 * q);
        x2 = fmaf(v.x, v.x, x2);
        x2 = fmaf(v.y, v.y, x2);
        x2 = fmaf(v.z, v.z, x2);
        x2 = fmaf(v.w, v.w, x2);
    }

    const float* __restrict__ wp  = cbk + (size_t)slice * (NCODE / NSLICE) * CH;
    const float* __restrict__ w2p = w2 + slice * (NCODE / NSLICE);

    float best  = 3.4e38f;
    int   bestk = 0;

    for (int kb = 0; kb < (NCODE / NSLICE) / KB; ++kb) {   // 32 k-blocks
        asm volatile("" : "+v"(xp));   // opaque per-iteration: blocks LICM hoist
        float acc[KB];
#pragma unroll
        for (int j = 0; j < KB; ++j) acc[j] = 0.f;

#pragma unroll
        for (int half = 0; half < 2; ++half) {
            float4v xv[8];                 // 32 channels of x, live this half only
#pragma unroll
            for (int q = 0; q < 8; ++q)
                xv[q] = *(const float4v*)(xp + half * 32 + 4 * q);

#pragma unroll
            for (int j = 0; j < KB; ++j) {
                const float* w = wp + (size_t)(kb * KB + j) * CH + half * 32; // scalar
#pragma unroll
                for (int q = 0; q < 8; ++q) {
                    acc[j] = fmaf(xv[q].x, w[4 * q + 0], acc[j]);
                    acc[j] = fmaf(xv[q].y, w[4 * q + 1], acc[j]);
                    acc[j] = fmaf(xv[q].z, w[4 * q + 2], acc[j]);
                    acc[j] = fmaf(xv[q].w, w[4 * q + 3], acc[j]);
                }
            }
        }

#pragma unroll
        for (int j = 0; j < KB; ++j) {
            int   k  = kb * KB + j;
            float d2 = (x2 - 2.0f * acc[j]) + w2p[k];
            if (d2 < best) { best = d2; bestk = k; }   // strict < = first-occurrence
        }
    }
    bestk += slice * (NCODE / NSLICE);

    __shared__ float  sbest[256];
    __shared__ int    skid[256];
    __shared__ double ssum[64];
    sbest[t] = best;
    skid[t]  = bestk;
    __syncthreads();

    if (slice == 0) {
        // Combine the K-slices in ascending-k order (preserves argmin ties).
#pragma unroll
        for (int s = 1; s < NSLICE; ++s) {
            float ob = sbest[pt + 64 * s];
            int   ok = skid[pt + 64 * s];
            if (ob < best) { best = ob; bestk = ok; }
        }
        idx_out[p] = (float)bestk;
        ssum[pt]   = (double)best;   // min d2 == ||x - quant||^2
    }
    __syncthreads();

    if (t == 0) {
        double s = 0.0;
        for (int i = 0; i < 64; ++i) s += ssum[i];
        partial[blockIdx.x] = s;
    }
}

// ---------------------------------------------------------------------------
// Kernel 3: quant_out[b,c,l] = codebook[idx[b,l], c]  (coalesced writes)
// ---------------------------------------------------------------------------
__global__ __launch_bounds__(256) void vq_gather(const float* __restrict__ cbk,
                                                 const float* __restrict__ idx_f,
                                                 float*       __restrict__ out) {
    int t  = blockIdx.x * 256 + threadIdx.x;   // over B*C*L
    int l  = t & (LEN - 1);
    int bc = t >> 12;
    int c  = bc & (CH - 1);
    int b  = bc >> 6;
    int k  = (int)idx_f[b * LEN + l];
    out[t] = cbk[(size_t)k * CH + c];
}

// ---------------------------------------------------------------------------
// Kernel 4: final loss reduction over the 1024 per-block partials.
// ---------------------------------------------------------------------------
__global__ __launch_bounds__(256) void vq_loss(const double* __restrict__ partial,
                                               float*        __restrict__ losses) {
    __shared__ double sred[256];
    double v = 0.0;
#pragma unroll
    for (int i = 0; i < 4; ++i) v += partial[threadIdx.x + 256 * i];
    sred[threadIdx.x] = v;
    __syncthreads();
    for (int s = 128; s > 0; s >>= 1) {
        if (threadIdx.x < s) sred[threadIdx.x] += sred[threadIdx.x + s];
        __syncthreads();
    }
    if (threadIdx.x == 0) {
        float loss = (float)(sred[0] / (double)((size_t)NPTS * CH));
        losses[0] = loss;   // codebook_loss
        losses[1] = loss;   // commitment_loss (same value)
    }
}

// ---------------------------------------------------------------------------
extern "C" void kernel_launch(void* const* d_in, const int* in_sizes, int n_in,
                              void* d_out, int out_size, void* d_ws, size_t ws_size,
                              hipStream_t stream) {
    const float* x  = (const float*)d_in[0];   // (B, C, L)
    const float* cb = (const float*)d_in[1];   // (K, C)
    float* out = (float*)d_out;

    // d_out layout: [quant_out (B*C*L)] [codebook_loss] [commitment_loss] [indices (B*L)]
    float* quant_out = out;
    float* losses    = out + (size_t)BATCH * CH * LEN;
    float* idx_out   = losses + 2;

    // workspace: [0,8KB) double partials; [8KB,12KB) w2; [16KB, 16KB+16MB) xt
    double* partial = (double*)d_ws;
    float*  w2      = (float*)((char*)d_ws + 8192);
    float*  xt      = (float*)((char*)d_ws + 16384);

    vq_transpose<<<BATCH * (LEN / 64), 256, 0, stream>>>(x, xt);
    vq_w2<<<NCODE / 256, 256, 0, stream>>>(cb, w2);
    vq_argmin<<<NPTS / 64, 256, 0, stream>>>(xt, cb, w2, idx_out, partial);
    vq_gather<<<(BATCH * CH * LEN) / 256, 256, 0, stream>>>(cb, idx_out, quant_out);
    vq_loss<<<1, 256, 0, stream>>>(partial, losses);
}

// Round 7
// 142.765 us; speedup vs baseline: 1.9111x; 1.9111x over previous
//
#include <hip/hip_runtime.h>

#define BATCH 16
#define CH    64
#define LEN   4096
#define NCODE 1024
#define NPTS  (BATCH * LEN)   // 65536
#define MT    64              // points per block
#define NT    64              // codes per n-tile
#define LDST  68              // LDS row stride (floats): 272B = 17*16B -> b128-aligned, conflict-benign

typedef float float4v __attribute__((ext_vector_type(4)));

// ---------------------------------------------------------------------------
// Kernel 1: w2[k] = sum_c codebook[k,c]^2
// ---------------------------------------------------------------------------
__global__ __launch_bounds__(256) void vq_w2(const float* __restrict__ cb,
                                             float* __restrict__ w2) {
    int k = blockIdx.x * 256 + threadIdx.x;
    if (k < NCODE) {
        const float* w = cb + (size_t)k * CH;
        float s = 0.f;
#pragma unroll
        for (int c = 0; c < CH; ++c) s = fmaf(w[c], w[c], s);
        w2[k] = s;
    }
}

// ---------------------------------------------------------------------------
// Kernel 2: LDS-tiled GEMM-style argmin.
// Block tile: 64 points x 64 codes x K=64, both operands staged in LDS.
// Thread (pg,cg) owns a 4x4 output patch; per k-step: 2 ds_read_b128 + 16 fmac.
// No value outlives one k-step -> nothing for the register allocator to
// remat/spill (rounds 2-6: thread-private x[64] was always sunk into the
// k-loop; VGPR stuck at 32-56 and L1 re-reads dominated).
// ---------------------------------------------------------------------------
__global__ __launch_bounds__(256, 4) void vq_argmin(const float*  __restrict__ x,
                                                    const float*  __restrict__ cbk,
                                                    const float*  __restrict__ w2,
                                                    float*        __restrict__ idx_out,
                                                    double*       __restrict__ partial) {
    __shared__ __attribute__((aligned(16))) float xs[CH * LDST];  // xs[ch][pt]
    __shared__ __attribute__((aligned(16))) float ws[CH * LDST];  // ws[ch][code]
    __shared__ double ssum[16];

    const int t  = threadIdx.x;
    const int cg = t & 15;        // code group  (lane bits 0..3)
    const int pg = t >> 4;        // point group 0..15
    const int p0 = blockIdx.x * MT;
    const int b  = p0 >> 12;      // / LEN
    const int l0 = p0 & (LEN - 1);

    // ---- stage x tile: xs[c][l] = x[b][c][l0+l]  (global x is [c][l]-contiguous)
    {
        const int c = t >> 2, q = t & 3;
        const float* src = x + ((size_t)b * CH + c) * LEN + l0 + q * 16;
        float* dst = &xs[c * LDST + q * 16];
#pragma unroll
        for (int j = 0; j < 4; ++j)
            *(float4v*)(dst + 4 * j) = *(const float4v*)(src + 4 * j);
    }
    __syncthreads();

    // ---- |x|^2 for my 4 points
    float x2[4] = {0.f, 0.f, 0.f, 0.f};
#pragma unroll
    for (int k = 0; k < CH; ++k) {
        float4v xa = *(const float4v*)&xs[k * LDST + 4 * pg];
        x2[0] = fmaf(xa.x, xa.x, x2[0]);
        x2[1] = fmaf(xa.y, xa.y, x2[1]);
        x2[2] = fmaf(xa.z, xa.z, x2[2]);
        x2[3] = fmaf(xa.w, xa.w, x2[3]);
    }

    float best[4]  = {3.4e38f, 3.4e38f, 3.4e38f, 3.4e38f};
    int   bestk[4] = {0, 0, 0, 0};

    for (int nt = 0; nt < NCODE / NT; ++nt) {
        __syncthreads();   // previous tile's ws reads complete
        // ---- stage w tile (transposed): ws[c][n] = cbk[nt*NT+n][c]
        {
            const int code = t & 63, cq = t >> 6;
            const float* src = cbk + ((size_t)(nt * NT + code)) * CH + cq * 16;
#pragma unroll
            for (int j = 0; j < 4; ++j) {
                float4v v = *(const float4v*)(src + 4 * j);
                ws[(cq * 16 + 4 * j + 0) * LDST + code] = v.x;
                ws[(cq * 16 + 4 * j + 1) * LDST + code] = v.y;
                ws[(cq * 16 + 4 * j + 2) * LDST + code] = v.z;
                ws[(cq * 16 + 4 * j + 3) * LDST + code] = v.w;
            }
        }
        __syncthreads();

        // ---- 4x4 dot-product patch
        float acc[4][4] = {{0.f}};
#pragma unroll
        for (int k = 0; k < CH; ++k) {
            float4v xa = *(const float4v*)&xs[k * LDST + 4 * pg];
            float4v wb = *(const float4v*)&ws[k * LDST + 4 * cg];
            acc[0][0] = fmaf(xa.x, wb.x, acc[0][0]);
            acc[0][1] = fmaf(xa.x, wb.y, acc[0][1]);
            acc[0][2] = fmaf(xa.x, wb.z, acc[0][2]);
            acc[0][3] = fmaf(xa.x, wb.w, acc[0][3]);
            acc[1][0] = fmaf(xa.y, wb.x, acc[1][0]);
            acc[1][1] = fmaf(xa.y, wb.y, acc[1][1]);
            acc[1][2] = fmaf(xa.y, wb.z, acc[1][2]);
            acc[1][3] = fmaf(xa.y, wb.w, acc[1][3]);
            acc[2][0] = fmaf(xa.z, wb.x, acc[2][0]);
            acc[2][1] = fmaf(xa.z, wb.y, acc[2][1]);
            acc[2][2] = fmaf(xa.z, wb.z, acc[2][2]);
            acc[2][3] = fmaf(xa.z, wb.w, acc[2][3]);
            acc[3][0] = fmaf(xa.w, wb.x, acc[3][0]);
            acc[3][1] = fmaf(xa.w, wb.y, acc[3][1]);
            acc[3][2] = fmaf(xa.w, wb.z, acc[3][2]);
            acc[3][3] = fmaf(xa.w, wb.w, acc[3][3]);
        }

        // ---- argmin update (this thread's codes, ascending k, strict <)
#pragma unroll
        for (int j = 0; j < 4; ++j) {
            int   k   = nt * NT + 4 * cg + j;
            float w2k = w2[k];
#pragma unroll
            for (int i = 0; i < 4; ++i) {
                float d2 = (x2[i] - 2.0f * acc[i][j]) + w2k;
                if (d2 < best[i]) { best[i] = d2; bestk[i] = k; }
            }
        }
    }

    // ---- butterfly across the 16 cg lanes (lane bits 0..3); smaller-k ties
#pragma unroll
    for (int m = 1; m < 16; m <<= 1) {
#pragma unroll
        for (int i = 0; i < 4; ++i) {
            float ob = __shfl_xor(best[i], m, 64);
            int   ok = __shfl_xor(bestk[i], m, 64);
            if (ob < best[i] || (ob == best[i] && ok < bestk[i])) {
                best[i] = ob; bestk[i] = ok;
            }
        }
    }

    if (cg == 0) {
        double s = 0.0;
#pragma unroll
        for (int i = 0; i < 4; ++i) {
            idx_out[p0 + 4 * pg + i] = (float)bestk[i];
            s += (double)best[i];          // min d2 == ||x - quant||^2
        }
        ssum[pg] = s;
    }
    __syncthreads();

    if (t == 0) {
        double s = 0.0;
#pragma unroll
        for (int i = 0; i < 16; ++i) s += ssum[i];
        partial[blockIdx.x] = s;
    }
}

// ---------------------------------------------------------------------------
// Kernel 3: quant_out[b,c,l] = codebook[idx[b,l], c]  (coalesced writes)
// ---------------------------------------------------------------------------
__global__ __launch_bounds__(256) void vq_gather(const float* __restrict__ cbk,
                                                 const float* __restrict__ idx_f,
                                                 float*       __restrict__ out) {
    int t  = blockIdx.x * 256 + threadIdx.x;   // over B*C*L
    int l  = t & (LEN - 1);
    int bc = t >> 12;
    int c  = bc & (CH - 1);
    int b  = bc >> 6;
    int k  = (int)idx_f[b * LEN + l];
    out[t] = cbk[(size_t)k * CH + c];
}

// ---------------------------------------------------------------------------
// Kernel 4: final loss reduction over the 1024 per-block partials.
// ---------------------------------------------------------------------------
__global__ __launch_bounds__(256) void vq_loss(const double* __restrict__ partial,
                                               float*        __restrict__ losses) {
    __shared__ double sred[256];
    double v = 0.0;
#pragma unroll
    for (int i = 0; i < 4; ++i) v += partial[threadIdx.x + 256 * i];
    sred[threadIdx.x] = v;
    __syncthreads();
    for (int s = 128; s > 0; s >>= 1) {
        if (threadIdx.x < s) sred[threadIdx.x] += sred[threadIdx.x + s];
        __syncthreads();
    }
    if (threadIdx.x == 0) {
        float loss = (float)(sred[0] / (double)((size_t)NPTS * CH));
        losses[0] = loss;   // codebook_loss
        losses[1] = loss;   // commitment_loss (same value)
    }
}

// ---------------------------------------------------------------------------
extern "C" void kernel_launch(void* const* d_in, const int* in_sizes, int n_in,
                              void* d_out, int out_size, void* d_ws, size_t ws_size,
                              hipStream_t stream) {
    const float* x  = (const float*)d_in[0];   // (B, C, L)
    const float* cb = (const float*)d_in[1];   // (K, C)
    float* out = (float*)d_out;

    // d_out layout: [quant_out (B*C*L)] [codebook_loss] [commitment_loss] [indices (B*L)]
    float* quant_out = out;
    float* losses    = out + (size_t)BATCH * CH * LEN;
    float* idx_out   = losses + 2;

    // workspace: [0, 8KB): double partials (1024); [8KB, 12KB): w2 (1024 floats)
    double* partial = (double*)d_ws;
    float*  w2      = (float*)((char*)d_ws + 8192);

    vq_w2<<<NCODE / 256, 256, 0, stream>>>(cb, w2);
    vq_argmin<<<NPTS / MT, 256, 0, stream>>>(x, cb, w2, idx_out, partial);
    vq_gather<<<(BATCH * CH * LEN) / 256, 256, 0, stream>>>(cb, idx_out, quant_out);
    vq_loss<<<1, 256, 0, stream>>>(partial, losses);
}